// Round 3
// baseline (165.327 us; speedup 1.0000x reference)
//
#include <hip/hip_runtime.h>
#include <math.h>

// GaussianMixture log-likelihood: ll[n] = logsumexp_m( wlog[m] - dx^T G_m dx )
// arg(n,m) = c0 + c1*x0^2 + c2*x0 + c3*x1^2 + c4*x1 + c5*x0*x1  (log2-scaled)
// R3: (a) prep detects m-uniform c1/c3/c5 (true when all A_m equal) -> inner
//     loop is 2 FMA/pair, per-sample base term added after logsumexp;
//     (b) M-split moved inside the block: 4 waves x same 64 samples, LDS
//     combine of (max, sum) partials -> no combine kernel, no P buffer;
//     (c) chunk 16 to amortize online-softmax rescale.

#if __has_builtin(__builtin_amdgcn_exp2f)
#define EXP2(x) __builtin_amdgcn_exp2f(x)
#else
#define EXP2(x) exp2f(x)
#endif

#define SPLIT 4
#define CH 16

__global__ __launch_bounds__(256) void prep_kernel(
    const float* __restrict__ mu,
    const float* __restrict__ A,
    const float* __restrict__ w,
    float* __restrict__ C,   // [6][M] planes + header {flag, cb1, cb3, cb5}
    int M) {
  __shared__ float red[256];
  __shared__ int uni[256];
  const int t = threadIdx.x;

  // log-softmax normalizer over w
  float mx = -INFINITY;
  for (int m = t; m < M; m += 256) mx = fmaxf(mx, w[m]);
  red[t] = mx; __syncthreads();
  for (int s = 128; s > 0; s >>= 1) {
    if (t < s) red[t] = fmaxf(red[t], red[t + s]);
    __syncthreads();
  }
  const float wmax = red[0]; __syncthreads();

  float sum = 0.f;
  for (int m = t; m < M; m += 256) sum += expf(w[m] - wmax);
  red[t] = sum; __syncthreads();
  for (int s = 128; s > 0; s >>= 1) {
    if (t < s) red[t] += red[t + s];
    __syncthreads();
  }
  const float logZ = wmax + logf(red[0]);

  // reference quadratic coeffs from component 0 (for uniformity detection)
  const float r00 = A[0], r01 = A[1], r10 = A[2], r11 = A[3];
  const float rg00 = 0.5f * (r00 * r00 + r01 * r01);
  const float rg01 = 0.5f * (r00 * r10 + r01 * r11);
  const float rg11 = 0.5f * (r10 * r10 + r11 * r11);

  const float LOG2E = 1.44269504088896340736f;
  int myuni = 1;
  for (int m = t; m < M; m += 256) {
    const float a00 = A[m * 4 + 0], a01 = A[m * 4 + 1];
    const float a10 = A[m * 4 + 2], a11 = A[m * 4 + 3];
    const float g00 = 0.5f * (a00 * a00 + a01 * a01);
    const float g01 = 0.5f * (a00 * a10 + a01 * a11);
    const float g11 = 0.5f * (a10 * a10 + a11 * a11);
    const float g01s = 2.0f * g01;
    const float det = g00 * g11 - g01 * g01;
    const float wlog = (w[m] - logZ) + 0.5f * logf(det);
    const float mu0 = mu[m * 2 + 0], mu1 = mu[m * 2 + 1];
    const float c0 = wlog - (g00 * mu0 * mu0 + g01s * mu0 * mu1 + g11 * mu1 * mu1);
    const float c2 = 2.0f * g00 * mu0 + g01s * mu1;
    const float c4 = 2.0f * g11 * mu1 + g01s * mu0;
    C[0 * M + m] = LOG2E * c0;
    C[1 * M + m] = LOG2E * -g00;
    C[2 * M + m] = LOG2E * c2;
    C[3 * M + m] = LOG2E * -g11;
    C[4 * M + m] = LOG2E * c4;
    C[5 * M + m] = LOG2E * -g01s;
    myuni &= (g00 == rg00) & (g01 == rg01) & (g11 == rg11);
  }
  uni[t] = myuni; __syncthreads();
  for (int s = 128; s > 0; s >>= 1) {
    if (t < s) uni[t] &= uni[t + s];
    __syncthreads();
  }
  if (t == 0) {
    ((int*)C)[6 * M + 0] = uni[0];
    C[6 * M + 1] = LOG2E * -rg00;        // cb1
    C[6 * M + 2] = LOG2E * -rg11;        // cb3
    C[6 * M + 3] = LOG2E * -2.0f * rg01; // cb5
  }
}

// One block = 64 samples x 4 waves; wave w covers components [w*M/4,(w+1)*M/4).
__global__ __launch_bounds__(256) void gmix_kernel(
    const float* __restrict__ sample,
    const float* __restrict__ C,
    float* __restrict__ out,
    int N, int M) {
  __shared__ float Lmx[SPLIT][64];
  __shared__ float Lsm[SPLIT][64];

  const int lane = threadIdx.x & 63;
  const int wave = threadIdx.x >> 6;
  const int n = blockIdx.x * 64 + lane;
  const bool valid = (n < N);

  const float2 x = valid ? ((const float2*)sample)[n] : make_float2(0.f, 0.f);
  const float x0 = x.x, x1 = x.y;

  const int flag = ((const int*)C)[6 * M + 0];
  const float cb1 = C[6 * M + 1];
  const float cb3 = C[6 * M + 2];
  const float cb5 = C[6 * M + 3];

  const int Mq = M / SPLIT;
  const int m0 = wave * Mq;
  const float* __restrict__ C0 = C + m0;
  const float* __restrict__ C1 = C + M + m0;
  const float* __restrict__ C2 = C + 2 * M + m0;
  const float* __restrict__ C3 = C + 3 * M + m0;
  const float* __restrict__ C4 = C + 4 * M + m0;
  const float* __restrict__ C5 = C + 5 * M + m0;

  float base = 0.0f;
  float mx = -INFINITY;
  float s = 0.0f;

  if (flag) {
    // uniform quadratic part: fold into per-sample base, 2 FMA per pair
    base = cb1 * x0 * x0 + cb3 * x1 * x1 + cb5 * x0 * x1;
    for (int m = 0; m < Mq; m += CH) {
      float a[CH];
#pragma unroll
      for (int j = 0; j < CH; ++j)
        a[j] = fmaf(C4[m + j], x1, fmaf(C2[m + j], x0, C0[m + j]));
      float cm = a[0];
#pragma unroll
      for (int j = 1; j < CH; ++j) cm = fmaxf(cm, a[j]);
      const float nm = fmaxf(mx, cm);
      s *= EXP2(mx - nm);
      float ls0 = 0.f, ls1 = 0.f;
#pragma unroll
      for (int j = 0; j < CH; j += 2) {
        ls0 += EXP2(a[j] - nm);
        ls1 += EXP2(a[j + 1] - nm);
      }
      s += ls0 + ls1;
      mx = nm;
    }
  } else {
    for (int m = 0; m < Mq; m += CH) {
      float a[CH];
#pragma unroll
      for (int j = 0; j < CH; ++j) {
        float t0 = fmaf(C1[m + j], x0, C2[m + j]);
        t0 = fmaf(C5[m + j], x1, t0);
        float t1 = fmaf(C3[m + j], x1, C4[m + j]);
        float r = fmaf(t0, x0, C0[m + j]);
        a[j] = fmaf(t1, x1, r);
      }
      float cm = a[0];
#pragma unroll
      for (int j = 1; j < CH; ++j) cm = fmaxf(cm, a[j]);
      const float nm = fmaxf(mx, cm);
      s *= EXP2(mx - nm);
      float ls0 = 0.f, ls1 = 0.f;
#pragma unroll
      for (int j = 0; j < CH; j += 2) {
        ls0 += EXP2(a[j] - nm);
        ls1 += EXP2(a[j + 1] - nm);
      }
      s += ls0 + ls1;
      mx = nm;
    }
  }

  Lmx[wave][lane] = mx;
  Lsm[wave][lane] = s;
  __syncthreads();

  if (wave == 0 && valid) {
    float m0v = Lmx[0][lane], m1v = Lmx[1][lane];
    float m2v = Lmx[2][lane], m3v = Lmx[3][lane];
    float gm = fmaxf(fmaxf(m0v, m1v), fmaxf(m2v, m3v));
    float S = Lsm[0][lane] * EXP2(m0v - gm)
            + Lsm[1][lane] * EXP2(m1v - gm)
            + Lsm[2][lane] * EXP2(m2v - gm)
            + Lsm[3][lane] * EXP2(m3v - gm);
    out[n] = (gm + __log2f(S) + base) * 0.69314718055994530942f;
  }
}

extern "C" void kernel_launch(void* const* d_in, const int* in_sizes, int n_in,
                              void* d_out, int out_size, void* d_ws, size_t ws_size,
                              hipStream_t stream) {
  const float* sample = (const float*)d_in[0];
  const float* mu     = (const float*)d_in[1];
  const float* A      = (const float*)d_in[2];
  const float* w      = (const float*)d_in[3];
  float* out = (float*)d_out;

  const int N = in_sizes[0] / 2;   // sample is (N,2)
  const int M = in_sizes[3];       // w is (M,1)

  float* C = (float*)d_ws;         // 6*M floats + 4-float header

  prep_kernel<<<1, 256, 0, stream>>>(mu, A, w, C, M);
  gmix_kernel<<<(N + 63) / 64, 256, 0, stream>>>(sample, C, out, N, M);
}

// Round 4
// 116.375 us; speedup vs baseline: 1.4206x; 1.4206x over previous
//
#include <hip/hip_runtime.h>
#include <math.h>

// GaussianMixture log-likelihood: ll[n] = logsumexp_m( wlog[m] - dx^T G_m dx )
// arg(n,m) = c0 + c1*x0^2 + c2*x0 + c3*x1^2 + c4*x1 + c5*x0*x1  (log2-scaled)
// R4: (a) wave id via readfirstlane -> coefficient reads provably wave-uniform
//     (s_load, not per-lane global_load: R3's 87->107us regression);
//     (b) 2 samples per thread (independent online-softmax chains) to amortize
//     scalar-coeff materialization and double ILP.
// Fast path (all A_m identical, detected on-device): 2 FMA per (sample,comp);
// quadratic term folded into per-sample base added after logsumexp.

#if __has_builtin(__builtin_amdgcn_exp2f)
#define EXP2(x) __builtin_amdgcn_exp2f(x)
#else
#define EXP2(x) exp2f(x)
#endif

#define SPLIT 4
#define CH 16

__global__ __launch_bounds__(256) void prep_kernel(
    const float* __restrict__ mu,
    const float* __restrict__ A,
    const float* __restrict__ w,
    float* __restrict__ C,   // [6][M] planes + header {flag, cb1, cb3, cb5}
    int M) {
  __shared__ float red[256];
  __shared__ int uni[256];
  const int t = threadIdx.x;

  float mx = -INFINITY;
  for (int m = t; m < M; m += 256) mx = fmaxf(mx, w[m]);
  red[t] = mx; __syncthreads();
  for (int s = 128; s > 0; s >>= 1) {
    if (t < s) red[t] = fmaxf(red[t], red[t + s]);
    __syncthreads();
  }
  const float wmax = red[0]; __syncthreads();

  float sum = 0.f;
  for (int m = t; m < M; m += 256) sum += expf(w[m] - wmax);
  red[t] = sum; __syncthreads();
  for (int s = 128; s > 0; s >>= 1) {
    if (t < s) red[t] += red[t + s];
    __syncthreads();
  }
  const float logZ = wmax + logf(red[0]);

  const float r00 = A[0], r01 = A[1], r10 = A[2], r11 = A[3];
  const float rg00 = 0.5f * (r00 * r00 + r01 * r01);
  const float rg01 = 0.5f * (r00 * r10 + r01 * r11);
  const float rg11 = 0.5f * (r10 * r10 + r11 * r11);

  const float LOG2E = 1.44269504088896340736f;
  int myuni = 1;
  for (int m = t; m < M; m += 256) {
    const float a00 = A[m * 4 + 0], a01 = A[m * 4 + 1];
    const float a10 = A[m * 4 + 2], a11 = A[m * 4 + 3];
    const float g00 = 0.5f * (a00 * a00 + a01 * a01);
    const float g01 = 0.5f * (a00 * a10 + a01 * a11);
    const float g11 = 0.5f * (a10 * a10 + a11 * a11);
    const float g01s = 2.0f * g01;
    const float det = g00 * g11 - g01 * g01;
    const float wlog = (w[m] - logZ) + 0.5f * logf(det);
    const float mu0 = mu[m * 2 + 0], mu1 = mu[m * 2 + 1];
    const float c0 = wlog - (g00 * mu0 * mu0 + g01s * mu0 * mu1 + g11 * mu1 * mu1);
    const float c2 = 2.0f * g00 * mu0 + g01s * mu1;
    const float c4 = 2.0f * g11 * mu1 + g01s * mu0;
    C[0 * M + m] = LOG2E * c0;
    C[1 * M + m] = LOG2E * -g00;
    C[2 * M + m] = LOG2E * c2;
    C[3 * M + m] = LOG2E * -g11;
    C[4 * M + m] = LOG2E * c4;
    C[5 * M + m] = LOG2E * -g01s;
    myuni &= (g00 == rg00) & (g01 == rg01) & (g11 == rg11);
  }
  uni[t] = myuni; __syncthreads();
  for (int s = 128; s > 0; s >>= 1) {
    if (t < s) uni[t] &= uni[t + s];
    __syncthreads();
  }
  if (t == 0) {
    ((int*)C)[6 * M + 0] = uni[0];
    C[6 * M + 1] = LOG2E * -rg00;        // cb1
    C[6 * M + 2] = LOG2E * -rg11;        // cb3
    C[6 * M + 3] = LOG2E * -2.0f * rg01; // cb5
  }
}

// One block = 128 samples x 4 waves; wave v covers components [v*M/4,(v+1)*M/4).
// Lane l handles samples (blk*128+l) and (blk*128+l+64).
__global__ __launch_bounds__(256) void gmix_kernel(
    const float* __restrict__ sample,
    const float* __restrict__ C,
    float* __restrict__ out,
    int N, int M) {
  __shared__ float Lmx[SPLIT][2][64];
  __shared__ float Lsm[SPLIT][2][64];

  const int lane = threadIdx.x & 63;
  const int wave = __builtin_amdgcn_readfirstlane(threadIdx.x >> 6);
  const int nA = blockIdx.x * 128 + lane;
  const int nB = nA + 64;

  const float2 xA = (nA < N) ? ((const float2*)sample)[nA] : make_float2(0.f, 0.f);
  const float2 xB = (nB < N) ? ((const float2*)sample)[nB] : make_float2(0.f, 0.f);
  const float xA0 = xA.x, xA1 = xA.y;
  const float xB0 = xB.x, xB1 = xB.y;

  const int flag = ((const int*)C)[6 * M + 0];
  const float cb1 = C[6 * M + 1];
  const float cb3 = C[6 * M + 2];
  const float cb5 = C[6 * M + 3];

  const int Mq = M / SPLIT;
  const int m0 = wave * Mq;                      // wave is SGPR -> scalar loads
  const float* __restrict__ C0 = C + m0;
  const float* __restrict__ C1 = C + M + m0;
  const float* __restrict__ C2 = C + 2 * M + m0;
  const float* __restrict__ C3 = C + 3 * M + m0;
  const float* __restrict__ C4 = C + 4 * M + m0;
  const float* __restrict__ C5 = C + 5 * M + m0;

  float baseA = 0.0f, baseB = 0.0f;
  float mxA = -INFINITY, sA = 0.0f;
  float mxB = -INFINITY, sB = 0.0f;

  if (flag) {
    baseA = cb1 * xA0 * xA0 + cb3 * xA1 * xA1 + cb5 * xA0 * xA1;
    baseB = cb1 * xB0 * xB0 + cb3 * xB1 * xB1 + cb5 * xB0 * xB1;
    for (int m = 0; m < Mq; m += CH) {
      float aA[CH], aB[CH];
#pragma unroll
      for (int j = 0; j < CH; ++j) {
        const float c0 = C0[m + j], c2 = C2[m + j], c4 = C4[m + j];
        aA[j] = fmaf(c4, xA1, fmaf(c2, xA0, c0));
        aB[j] = fmaf(c4, xB1, fmaf(c2, xB0, c0));
      }
      float cmA = aA[0], cmB = aB[0];
#pragma unroll
      for (int j = 1; j < CH; ++j) { cmA = fmaxf(cmA, aA[j]); cmB = fmaxf(cmB, aB[j]); }
      const float nmA = fmaxf(mxA, cmA);
      const float nmB = fmaxf(mxB, cmB);
      sA *= EXP2(mxA - nmA);
      sB *= EXP2(mxB - nmB);
      float lA0 = 0.f, lA1 = 0.f, lB0 = 0.f, lB1 = 0.f;
#pragma unroll
      for (int j = 0; j < CH; j += 2) {
        lA0 += EXP2(aA[j] - nmA);
        lA1 += EXP2(aA[j + 1] - nmA);
        lB0 += EXP2(aB[j] - nmB);
        lB1 += EXP2(aB[j + 1] - nmB);
      }
      sA += lA0 + lA1; mxA = nmA;
      sB += lB0 + lB1; mxB = nmB;
    }
  } else {
    for (int m = 0; m < Mq; m += CH) {
      float aA[CH], aB[CH];
#pragma unroll
      for (int j = 0; j < CH; ++j) {
        const float c0 = C0[m + j], c1 = C1[m + j], c2 = C2[m + j];
        const float c3 = C3[m + j], c4 = C4[m + j], c5 = C5[m + j];
        float tA0 = fmaf(c1, xA0, c2); tA0 = fmaf(c5, xA1, tA0);
        float tA1 = fmaf(c3, xA1, c4);
        aA[j] = fmaf(tA1, xA1, fmaf(tA0, xA0, c0));
        float tB0 = fmaf(c1, xB0, c2); tB0 = fmaf(c5, xB1, tB0);
        float tB1 = fmaf(c3, xB1, c4);
        aB[j] = fmaf(tB1, xB1, fmaf(tB0, xB0, c0));
      }
      float cmA = aA[0], cmB = aB[0];
#pragma unroll
      for (int j = 1; j < CH; ++j) { cmA = fmaxf(cmA, aA[j]); cmB = fmaxf(cmB, aB[j]); }
      const float nmA = fmaxf(mxA, cmA);
      const float nmB = fmaxf(mxB, cmB);
      sA *= EXP2(mxA - nmA);
      sB *= EXP2(mxB - nmB);
      float lA0 = 0.f, lA1 = 0.f, lB0 = 0.f, lB1 = 0.f;
#pragma unroll
      for (int j = 0; j < CH; j += 2) {
        lA0 += EXP2(aA[j] - nmA);
        lA1 += EXP2(aA[j + 1] - nmA);
        lB0 += EXP2(aB[j] - nmB);
        lB1 += EXP2(aB[j + 1] - nmB);
      }
      sA += lA0 + lA1; mxA = nmA;
      sB += lB0 + lB1; mxB = nmB;
    }
  }

  Lmx[wave][0][lane] = mxA; Lsm[wave][0][lane] = sA;
  Lmx[wave][1][lane] = mxB; Lsm[wave][1][lane] = sB;
  __syncthreads();

  // wave 0 finalizes sample set A (its own baseA), wave 1 set B (its own baseB)
  if (wave < 2) {
    const int set = wave;
    const int n = blockIdx.x * 128 + set * 64 + lane;
    if (n < N) {
      const float base = (set == 0) ? baseA : baseB;
      float m0v = Lmx[0][set][lane], m1v = Lmx[1][set][lane];
      float m2v = Lmx[2][set][lane], m3v = Lmx[3][set][lane];
      float gm = fmaxf(fmaxf(m0v, m1v), fmaxf(m2v, m3v));
      float S = Lsm[0][set][lane] * EXP2(m0v - gm)
              + Lsm[1][set][lane] * EXP2(m1v - gm)
              + Lsm[2][set][lane] * EXP2(m2v - gm)
              + Lsm[3][set][lane] * EXP2(m3v - gm);
      out[n] = (gm + __log2f(S) + base) * 0.69314718055994530942f;
    }
  }
}

extern "C" void kernel_launch(void* const* d_in, const int* in_sizes, int n_in,
                              void* d_out, int out_size, void* d_ws, size_t ws_size,
                              hipStream_t stream) {
  const float* sample = (const float*)d_in[0];
  const float* mu     = (const float*)d_in[1];
  const float* A      = (const float*)d_in[2];
  const float* w      = (const float*)d_in[3];
  float* out = (float*)d_out;

  const int N = in_sizes[0] / 2;   // sample is (N,2)
  const int M = in_sizes[3];       // w is (M,1)

  float* C = (float*)d_ws;         // 6*M floats + 4-float header

  prep_kernel<<<1, 256, 0, stream>>>(mu, A, w, C, M);
  gmix_kernel<<<(N + 127) / 128, 256, 0, stream>>>(sample, C, out, N, M);
}

// Round 6
// 109.322 us; speedup vs baseline: 1.5123x; 1.0645x over previous
//
#include <hip/hip_runtime.h>
#include <math.h>

// GaussianMixture log-likelihood: ll[n] = logsumexp_m( wlog[m] - dx^T G_m dx )
// arg(n,m) = c0 + c1*x0^2 + c2*x0 + c3*x1^2 + c4*x1 + c5*x0*x1  (log2-scaled)
// R6: R5 structure (packed fp32 two-sample inner loop, 8-wave in-block M
// split, base folded into stored partial max) with the R5 NaN bug fixed:
// the chunk max MUST cover every element (R5's strided tree skipped 4/16 ->
// exp2 overflow -> inf*0=NaN in combine). Now a complete packed max tree
// via __builtin_elementwise_max (v_pk_max_f32).
// readfirstlane on wave id keeps coefficient loads scalar (R3 lesson).

#if __has_builtin(__builtin_amdgcn_exp2f)
#define EXP2(x) __builtin_amdgcn_exp2f(x)
#else
#define EXP2(x) exp2f(x)
#endif

typedef float v2f __attribute__((ext_vector_type(2)));

#if __has_builtin(__builtin_elementwise_max)
#define PKMAX(a, b) __builtin_elementwise_max(a, b)
#else
static __device__ inline v2f PKMAX(v2f a, v2f b) {
  v2f r; r.x = fmaxf(a.x, b.x); r.y = fmaxf(a.y, b.y); return r;
}
#endif

#define SPLIT 8
#define CH 16

__global__ __launch_bounds__(256) void prep_kernel(
    const float* __restrict__ mu,
    const float* __restrict__ A,
    const float* __restrict__ w,
    float* __restrict__ C,   // [6][M] planes + header {flag, cb1, cb3, cb5}
    int M) {
  __shared__ float red[256];
  __shared__ int uni[256];
  const int t = threadIdx.x;

  float mx = -INFINITY;
  for (int m = t; m < M; m += 256) mx = fmaxf(mx, w[m]);
  red[t] = mx; __syncthreads();
  for (int s = 128; s > 0; s >>= 1) {
    if (t < s) red[t] = fmaxf(red[t], red[t + s]);
    __syncthreads();
  }
  const float wmax = red[0]; __syncthreads();

  float sum = 0.f;
  for (int m = t; m < M; m += 256) sum += expf(w[m] - wmax);
  red[t] = sum; __syncthreads();
  for (int s = 128; s > 0; s >>= 1) {
    if (t < s) red[t] += red[t + s];
    __syncthreads();
  }
  const float logZ = wmax + logf(red[0]);

  const float r00 = A[0], r01 = A[1], r10 = A[2], r11 = A[3];
  const float rg00 = 0.5f * (r00 * r00 + r01 * r01);
  const float rg01 = 0.5f * (r00 * r10 + r01 * r11);
  const float rg11 = 0.5f * (r10 * r10 + r11 * r11);

  const float LOG2E = 1.44269504088896340736f;
  int myuni = 1;
  for (int m = t; m < M; m += 256) {
    const float a00 = A[m * 4 + 0], a01 = A[m * 4 + 1];
    const float a10 = A[m * 4 + 2], a11 = A[m * 4 + 3];
    const float g00 = 0.5f * (a00 * a00 + a01 * a01);
    const float g01 = 0.5f * (a00 * a10 + a01 * a11);
    const float g11 = 0.5f * (a10 * a10 + a11 * a11);
    const float g01s = 2.0f * g01;
    const float det = g00 * g11 - g01 * g01;
    const float wlog = (w[m] - logZ) + 0.5f * logf(det);
    const float mu0 = mu[m * 2 + 0], mu1 = mu[m * 2 + 1];
    const float c0 = wlog - (g00 * mu0 * mu0 + g01s * mu0 * mu1 + g11 * mu1 * mu1);
    const float c2 = 2.0f * g00 * mu0 + g01s * mu1;
    const float c4 = 2.0f * g11 * mu1 + g01s * mu0;
    C[0 * M + m] = LOG2E * c0;
    C[1 * M + m] = LOG2E * -g00;
    C[2 * M + m] = LOG2E * c2;
    C[3 * M + m] = LOG2E * -g11;
    C[4 * M + m] = LOG2E * c4;
    C[5 * M + m] = LOG2E * -g01s;
    myuni &= (g00 == rg00) & (g01 == rg01) & (g11 == rg11);
  }
  uni[t] = myuni; __syncthreads();
  for (int s = 128; s > 0; s >>= 1) {
    if (t < s) uni[t] &= uni[t + s];
    __syncthreads();
  }
  if (t == 0) {
    ((int*)C)[6 * M + 0] = uni[0];
    C[6 * M + 1] = LOG2E * -rg00;        // cb1
    C[6 * M + 2] = LOG2E * -rg11;        // cb3
    C[6 * M + 3] = LOG2E * -2.0f * rg01; // cb5
  }
}

// One block = 512 threads = 8 waves; all waves cover the SAME 128 samples
// (lane l -> samples blk*128+l and +64), wave v covers comps [v*M/8,(v+1)*M/8).
__global__ __launch_bounds__(512) void gmix_kernel(
    const float* __restrict__ sample,
    const float* __restrict__ C,
    float* __restrict__ out,
    int N, int M) {
  __shared__ float Lmx[SPLIT][2][64];
  __shared__ float Lsm[SPLIT][2][64];

  const int lane = threadIdx.x & 63;
  const int wave = __builtin_amdgcn_readfirstlane((int)(threadIdx.x >> 6));
  const int nA = blockIdx.x * 128 + lane;
  const int nB = nA + 64;

  const float2 xA = (nA < N) ? ((const float2*)sample)[nA] : make_float2(0.f, 0.f);
  const float2 xB = (nB < N) ? ((const float2*)sample)[nB] : make_float2(0.f, 0.f);
  const v2f x0p = {xA.x, xB.x};   // lo = sample A, hi = sample B
  const v2f x1p = {xA.y, xB.y};

  const int flag = ((const int*)C)[6 * M + 0];
  const float cb1 = C[6 * M + 1];
  const float cb3 = C[6 * M + 2];
  const float cb5 = C[6 * M + 3];

  const int Mq = M / SPLIT;
  const int m0 = wave * Mq;                      // SGPR -> scalar loads
  const float* __restrict__ C0 = C + m0;
  const float* __restrict__ C1 = C + M + m0;
  const float* __restrict__ C2 = C + 2 * M + m0;
  const float* __restrict__ C3 = C + 3 * M + m0;
  const float* __restrict__ C4 = C + 4 * M + m0;
  const float* __restrict__ C5 = C + 5 * M + m0;

  v2f basep = {0.f, 0.f};
  float mxA = -INFINITY, sA = 0.0f;
  float mxB = -INFINITY, sB = 0.0f;

  if (flag) {
    basep = cb1 * x0p * x0p + cb3 * x1p * x1p + cb5 * x0p * x1p;
    for (int m = 0; m < Mq; m += CH) {
      v2f a[CH];
#pragma unroll
      for (int j = 0; j < CH; ++j) {
        const float c0 = C0[m + j], c2 = C2[m + j], c4 = C4[m + j];
        v2f t = x0p * c2 + c0;     // v_pk_fma_f32
        a[j] = x1p * c4 + t;       // v_pk_fma_f32
      }
      // COMPLETE packed max tree over all CH elements (R5 bug: partial
      // coverage -> exp2 overflow -> inf*0 NaN in combine)
      v2f cm01 = PKMAX(a[0], a[1]);
      v2f cm23 = PKMAX(a[2], a[3]);
      v2f cm45 = PKMAX(a[4], a[5]);
      v2f cm67 = PKMAX(a[6], a[7]);
#pragma unroll
      for (int j = 8; j < CH; j += 4) {
        cm01 = PKMAX(cm01, a[j]);
        cm23 = PKMAX(cm23, a[j + 1]);
        cm45 = PKMAX(cm45, a[j + 2]);
        cm67 = PKMAX(cm67, a[j + 3]);
      }
      const v2f cm = PKMAX(PKMAX(cm01, cm23), PKMAX(cm45, cm67));
      const float nmA = fmaxf(mxA, cm.x);
      const float nmB = fmaxf(mxB, cm.y);
      sA *= EXP2(mxA - nmA);
      sB *= EXP2(mxB - nmB);
      const v2f nmp = {nmA, nmB};
      float lA0 = 0.f, lA1 = 0.f, lB0 = 0.f, lB1 = 0.f;
#pragma unroll
      for (int j = 0; j < CH; j += 2) {
        const v2f d0 = a[j] - nmp;       // v_pk_add_f32
        const v2f d1 = a[j + 1] - nmp;
        lA0 += EXP2(d0.x);
        lB0 += EXP2(d0.y);
        lA1 += EXP2(d1.x);
        lB1 += EXP2(d1.y);
      }
      sA += lA0 + lA1; mxA = nmA;
      sB += lB0 + lB1; mxB = nmB;
    }
  } else {
    for (int m = 0; m < Mq; m += CH) {
      v2f a[CH];
#pragma unroll
      for (int j = 0; j < CH; ++j) {
        const float c0 = C0[m + j], c1 = C1[m + j], c2 = C2[m + j];
        const float c3 = C3[m + j], c4 = C4[m + j], c5 = C5[m + j];
        v2f t0 = x0p * c1 + c2;
        t0 = x1p * c5 + t0;
        v2f t1 = x1p * c3 + c4;
        v2f r = t0 * x0p + c0;
        a[j] = t1 * x1p + r;
      }
      v2f cm01 = PKMAX(a[0], a[1]);
      v2f cm23 = PKMAX(a[2], a[3]);
      v2f cm45 = PKMAX(a[4], a[5]);
      v2f cm67 = PKMAX(a[6], a[7]);
#pragma unroll
      for (int j = 8; j < CH; j += 4) {
        cm01 = PKMAX(cm01, a[j]);
        cm23 = PKMAX(cm23, a[j + 1]);
        cm45 = PKMAX(cm45, a[j + 2]);
        cm67 = PKMAX(cm67, a[j + 3]);
      }
      const v2f cm = PKMAX(PKMAX(cm01, cm23), PKMAX(cm45, cm67));
      const float nmA = fmaxf(mxA, cm.x);
      const float nmB = fmaxf(mxB, cm.y);
      sA *= EXP2(mxA - nmA);
      sB *= EXP2(mxB - nmB);
      const v2f nmp = {nmA, nmB};
      float lA0 = 0.f, lA1 = 0.f, lB0 = 0.f, lB1 = 0.f;
#pragma unroll
      for (int j = 0; j < CH; j += 2) {
        const v2f d0 = a[j] - nmp;
        const v2f d1 = a[j + 1] - nmp;
        lA0 += EXP2(d0.x);
        lB0 += EXP2(d0.y);
        lA1 += EXP2(d1.x);
        lB1 += EXP2(d1.y);
      }
      sA += lA0 + lA1; mxA = nmA;
      sB += lB0 + lB1; mxB = nmB;
    }
  }

  // fold per-sample base into the partial max: logsumexp shifts uniformly
  Lmx[wave][0][lane] = mxA + basep.x; Lsm[wave][0][lane] = sA;
  Lmx[wave][1][lane] = mxB + basep.y; Lsm[wave][1][lane] = sB;
  __syncthreads();

  if (wave < 2) {
    const int set = wave;
    const int n = blockIdx.x * 128 + set * 64 + lane;
    if (n < N) {
      float gm = Lmx[0][set][lane];
#pragma unroll
      for (int v = 1; v < SPLIT; ++v) gm = fmaxf(gm, Lmx[v][set][lane]);
      float S = 0.f;
#pragma unroll
      for (int v = 0; v < SPLIT; ++v)
        S += Lsm[v][set][lane] * EXP2(Lmx[v][set][lane] - gm);
      out[n] = (gm + __log2f(S)) * 0.69314718055994530942f;
    }
  }
}

extern "C" void kernel_launch(void* const* d_in, const int* in_sizes, int n_in,
                              void* d_out, int out_size, void* d_ws, size_t ws_size,
                              hipStream_t stream) {
  const float* sample = (const float*)d_in[0];
  const float* mu     = (const float*)d_in[1];
  const float* A      = (const float*)d_in[2];
  const float* w      = (const float*)d_in[3];
  float* out = (float*)d_out;

  const int N = in_sizes[0] / 2;   // sample is (N,2)
  const int M = in_sizes[3];       // w is (M,1)

  float* C = (float*)d_ws;         // 6*M floats + 4-float header

  prep_kernel<<<1, 256, 0, stream>>>(mu, A, w, C, M);
  gmix_kernel<<<(N + 127) / 128, 512, 0, stream>>>(sample, C, out, N, M);
}